// Round 5
// baseline (208.454 us; speedup 1.0000x reference)
//
#include <hip/hip_runtime.h>
#include <math.h>

// BioTripletLoss: B=16384 rows, D=1024 fp32.
// pos_dist[i] = ||h[i]+r[i]-t[i]||, neg_dist[i] = ||h[i]+r[i]-t[neg_idx[i]]||
// dissim (rel==1): relu(0.6 - pos) + 0.5*exp(-pos)
// sim:             relu(pos - neg + 0.3) + 0.3*relu(0.1 - pos)
// out = mean(per_sample)
//
// R5 (= R4 with compile fix): kernel time is invariant (~75-80us) across
// MLP/occupancy restructurings AND invariant to HBM-vs-L3 residency =>
// on-chip per-CU read-path ceiling (~5.6 B/cy/CU = 3.4 TB/s device read).
// Attempt to move it: nontemporal loads on the once-read h/r streams
// (native ext_vector_type needed — HIP float4 is rejected by the builtin);
// alias the gather to the t-row for dissim rows (wave-uniform rel ->
// those ~10% of gather loads become L1 hits).

#define BDIM 16384
#define DDIM 1024

typedef float vfloat4 __attribute__((ext_vector_type(4)));

__global__ void zero_out_kernel(float* __restrict__ out) { out[0] = 0.0f; }

__global__ __launch_bounds__(256) void triplet_fused_kernel(
    const float* __restrict__ h, const float* __restrict__ t,
    const float* __restrict__ r, const int* __restrict__ rel,
    const int* __restrict__ neg, float* __restrict__ out)
{
    const int wave = threadIdx.x >> 6;
    const int lane = threadIdx.x & 63;
    const int row  = (blockIdx.x << 2) + wave;

    // row is wave-uniform -> these lower to scalar K$ loads
    const int nidx = neg[row];
    const int rl   = rel[row];

    const vfloat4* h4 = (const vfloat4*)(h + (size_t)row * DDIM);
    const vfloat4* r4 = (const vfloat4*)(r + (size_t)row * DDIM);
    const vfloat4* t4 = (const vfloat4*)(t + (size_t)row * DDIM);
    // dissim rows never use neg_dist: alias gather to own t row -> L1 hits
    const vfloat4* n4 = (rl == 1) ? t4 : (const vfloat4*)(t + (size_t)nidx * DDIM);

    float psum = 0.0f, nsum = 0.0f;
#pragma unroll
    for (int j = 0; j < 4; ++j) {
        const int k = lane + (j << 6);   // float4 index 0..255
        vfloat4 hv = __builtin_nontemporal_load(&h4[k]);  // touched once: nt
        vfloat4 rv = __builtin_nontemporal_load(&r4[k]);  // touched once: nt
        vfloat4 tv = t4[k];   // t read twice kernel-wide (stream + gather): cached
        vfloat4 nv = n4[k];

        vfloat4 a = hv + rv;
        vfloat4 d = a - tv;
        psum += d.x * d.x + d.y * d.y + d.z * d.z + d.w * d.w;
        vfloat4 e = a - nv;
        nsum += e.x * e.x + e.y * e.y + e.z * e.z + e.w * e.w;
    }

    // wave-64 butterfly reduction
#pragma unroll
    for (int off = 32; off > 0; off >>= 1) {
        psum += __shfl_down(psum, off, 64);
        nsum += __shfl_down(nsum, off, 64);
    }

    __shared__ float sm[4];
    if (lane == 0) {
        float pos = sqrtf(psum);
        float negd = sqrtf(nsum);
        float loss;
        if (rl == 1) loss = fmaxf(0.6f - pos, 0.0f) + 0.5f * expf(-pos);
        else         loss = fmaxf(pos - negd + 0.3f, 0.0f)
                          + 0.3f * fmaxf(0.1f - pos, 0.0f);
        sm[wave] = loss;
    }
    __syncthreads();
    if (threadIdx.x == 0) {
        float blk = (sm[0] + sm[1] + sm[2] + sm[3]) * (1.0f / (float)BDIM);
        atomicAdd(out, blk);   // device-scope by default on CDNA
    }
}

extern "C" void kernel_launch(void* const* d_in, const int* in_sizes, int n_in,
                              void* d_out, int out_size, void* d_ws, size_t ws_size,
                              hipStream_t stream) {
    const float* h = (const float*)d_in[0];
    const float* t = (const float*)d_in[1];
    const float* r = (const float*)d_in[2];
    const int* rel = (const int*)d_in[3];
    const int* neg = (const int*)d_in[4];
    float* out = (float*)d_out;

    zero_out_kernel<<<1, 1, 0, stream>>>(out);
    triplet_fused_kernel<<<BDIM / 4, 256, 0, stream>>>(h, t, r, rel, neg, out);
}

// Round 7
// 205.727 us; speedup vs baseline: 1.0133x; 1.0133x over previous
//
#include <hip/hip_runtime.h>
#include <math.h>

// BioTripletLoss: B=16384 rows, D=1024 fp32.
// pos_dist[i] = ||h[i]+r[i]-t[i]||, neg_dist[i] = ||h[i]+r[i]-t[neg_idx[i]]||
// dissim (rel==1): relu(0.6 - pos) + 0.5*exp(-pos)
// sim:             relu(pos - neg + 0.3) + 0.3*relu(0.1 - pos)
// out = mean(per_sample)
//
// R7 (= R6 with waitcnt as compile-time constants): VGPR-return load path
// saturates at ~6.3 B/cy/CU (time invariant to MLP/occupancy AND to
// HBM-vs-L3 residency). Switch bulk traffic to the global_load_lds DMA
// path (m97 GEMM sustains ~21 B/cy/CU through it). Per wave: own 8 KB LDS
// slice = 2 buffers x 4 streams x 1 KB chunks, double-buffered with manual
// s_waitcnt vmcnt(4); no __syncthreads needed (each lane reads back
// exactly the bytes it DMA'd: dest = base + lane*16).

#define BDIM 16384
#define DDIM 1024

typedef float vfloat4 __attribute__((ext_vector_type(4)));

// global->LDS DMA, 16 B per lane; lds dest is wave-uniform base + lane*16
#define GLD_LDS(gsrc, ldst)                                                  \
    __builtin_amdgcn_global_load_lds(                                        \
        (const __attribute__((address_space(1))) void*)(gsrc),               \
        (__attribute__((address_space(3))) void*)(ldst), 16, 0, 0)

// s_waitcnt imm (gfx9 encoding): vmcnt[3:0] | expcnt[6:4] | lgkmcnt[11:8]
#define WAITCNT_VM4 0x0F74   // vmcnt(4), lgkm/exp no-wait
#define WAITCNT_VM0 0x0F70   // vmcnt(0), lgkm/exp no-wait

__global__ void zero_out_kernel(float* __restrict__ out) { out[0] = 0.0f; }

__global__ __launch_bounds__(256) void triplet_lds_kernel(
    const float* __restrict__ h, const float* __restrict__ t,
    const float* __restrict__ r, const int* __restrict__ rel,
    const int* __restrict__ neg, float* __restrict__ out)
{
    // per wave: 2 buffers x 4 KB (4 streams x 1 KB); 4 waves -> 32 KB
    __shared__ __align__(16) char smem[4 * 8192];
    __shared__ float sm[4];

    const int wave = threadIdx.x >> 6;
    const int lane = threadIdx.x & 63;
    const int row  = (blockIdx.x << 2) + wave;

    const int nidx = neg[row];
    const int rl   = rel[row];

    const float* hb = h + (size_t)row * DDIM;
    const float* rb = r + (size_t)row * DDIM;
    const float* tb = t + (size_t)row * DDIM;
    // dissim rows never use neg_dist: alias gather to own t row
    const float* nb = (rl == 1) ? tb : t + (size_t)nidx * DDIM;

    char* base = smem + (wave << 13);   // 8 KB per wave

    // issue the 4 stream-chunks (1 KB each) of chunk c into buffer b
    auto issue = [&](int c, int b) {
        const int go = (c << 8) + (lane << 2);   // float offset in row
        char* lb = base + (b << 12);
        GLD_LDS(hb + go, lb);
        GLD_LDS(rb + go, lb + 1024);
        GLD_LDS(tb + go, lb + 2048);
        GLD_LDS(nb + go, lb + 3072);
    };

    issue(0, 0);
    float psum = 0.0f, nsum = 0.0f;
#pragma unroll
    for (int c = 0; c < 4; ++c) {
        if (c < 3) {
            issue(c + 1, (c + 1) & 1);
            // wait for chunk c's 4 DMAs (oldest of 8 outstanding)
            __builtin_amdgcn_s_waitcnt(WAITCNT_VM4);
        } else {
            __builtin_amdgcn_s_waitcnt(WAITCNT_VM0);
        }
        __builtin_amdgcn_sched_barrier(0);   // don't hoist ds_read above wait
        const char* lb = base + ((c & 1) << 12);
        const int lo = lane << 4;
        vfloat4 hv = *(const vfloat4*)(lb + lo);
        vfloat4 rv = *(const vfloat4*)(lb + 1024 + lo);
        vfloat4 tv = *(const vfloat4*)(lb + 2048 + lo);
        vfloat4 nv = *(const vfloat4*)(lb + 3072 + lo);
        vfloat4 a = hv + rv;
        vfloat4 d = a - tv;
        vfloat4 e = a - nv;
        psum += d.x * d.x + d.y * d.y + d.z * d.z + d.w * d.w;
        nsum += e.x * e.x + e.y * e.y + e.z * e.z + e.w * e.w;
    }

    // wave-64 butterfly reduction
#pragma unroll
    for (int off = 32; off > 0; off >>= 1) {
        psum += __shfl_down(psum, off, 64);
        nsum += __shfl_down(nsum, off, 64);
    }

    if (lane == 0) {
        float pos = sqrtf(psum);
        float negd = sqrtf(nsum);
        float loss;
        if (rl == 1) loss = fmaxf(0.6f - pos, 0.0f) + 0.5f * expf(-pos);
        else         loss = fmaxf(pos - negd + 0.3f, 0.0f)
                          + 0.3f * fmaxf(0.1f - pos, 0.0f);
        sm[wave] = loss;
    }
    __syncthreads();
    if (threadIdx.x == 0) {
        float blk = (sm[0] + sm[1] + sm[2] + sm[3]) * (1.0f / (float)BDIM);
        atomicAdd(out, blk);   // device-scope by default on CDNA
    }
}

extern "C" void kernel_launch(void* const* d_in, const int* in_sizes, int n_in,
                              void* d_out, int out_size, void* d_ws, size_t ws_size,
                              hipStream_t stream) {
    const float* h = (const float*)d_in[0];
    const float* t = (const float*)d_in[1];
    const float* r = (const float*)d_in[2];
    const int* rel = (const int*)d_in[3];
    const int* neg = (const int*)d_in[4];
    float* out = (float*)d_out;

    zero_out_kernel<<<1, 1, 0, stream>>>(out);
    triplet_lds_kernel<<<BDIM / 4, 256, 0, stream>>>(h, t, r, rel, neg, out);
}